// Round 2
// baseline (17207.935 us; speedup 1.0000x reference)
//
#include <hip/hip_runtime.h>
#include <float.h>

#define NB 64
#define NP 1024
#define KNN 10

__device__ __forceinline__ float lrelu(float v){ return v >= 0.0f ? v : 0.01f*v; }

// ---------------- zero fmean (harness poisons ws each launch) ----------------
__global__ void zero_fmean(float* __restrict__ f){
  int i = blockIdx.x*256 + threadIdx.x;
  if (i < NB*192) f[i] = 0.0f;
}

// ---------------- prep: transpose small weights ----------------
// wat[o*8+c]=w1a[c*64+o]; wbt[o*64+c]=w1b[c*64+o]; wct[o*64+c]=w1c[c*64+o]
__global__ void prep1_kernel(const float* __restrict__ w1a, const float* __restrict__ w1b,
                             const float* __restrict__ w1c,
                             float* __restrict__ wat, float* __restrict__ wbt,
                             float* __restrict__ wct){
  int tid = blockIdx.x*256 + threadIdx.x;
  if (tid < 512){
    int o = tid >> 3, c = tid & 7;
    wat[tid] = w1a[c*64 + o];
  } else if (tid < 4608){
    int i = tid - 512; int o = i >> 6, c = i & 63;
    wbt[i] = w1b[c*64 + o];
  } else if (tid < 8704){
    int i = tid - 4608; int o = i >> 6, c = i & 63;
    wct[i] = w1c[c*64 + o];
  }
}

// wcomb[op*64+c]: op<128 -> W_bot[c][op] = w2[(64+c)*128+op]
//                 op>=128 -> (W_top - W_bot)[c][op-128]
__global__ void prep2_kernel(const float* __restrict__ w2, float* __restrict__ wcomb){
  int tid = blockIdx.x*256 + threadIdx.x;  // 16384
  int op = tid >> 6, c = tid & 63;
  if (op < 128){
    wcomb[tid] = w2[(64+c)*128 + op];
  } else {
    int o = op - 128;
    wcomb[tid] = w2[c*128 + o] - w2[(64+c)*128 + o];
  }
}

// ---------------- build xx = concat(x, pos) ----------------
__global__ void build_xx(const float* __restrict__ x, const float* __restrict__ pos,
                         float* __restrict__ xx){
  int n = blockIdx.x*256 + threadIdx.x;
  float4 v;
  v.x = x[n];
  v.y = pos[3*n+0];
  v.z = pos[3*n+1];
  v.w = pos[3*n+2];
  ((float4*)xx)[n] = v;
}

// ---------------- knn on 4-dim features ----------------
__global__ __launch_bounds__(256,4) void knn1_kernel(const float* __restrict__ xx,
                                                     int* __restrict__ idx1){
  __shared__ alignas(16) float sf[NP*4];
  __shared__ float ssq[NP];
  int b = blockIdx.x >> 2;
  int q = blockIdx.x & 3;
  const float4* base = (const float4*)(xx + (size_t)b*NP*4);
  for (int t = threadIdx.x; t < NP; t += 256){
    float4 v = base[t];
    ((float4*)sf)[t] = v;
    ssq[t] = ((v.x*v.x + v.y*v.y) + v.z*v.z) + v.w*v.w;
  }
  __syncthreads();
  int il = q*256 + threadIdx.x;
  float4 fi = ((float4*)sf)[il];
  float sqi = ssq[il];
  float bd[KNN]; int bi[KNN];
  #pragma unroll
  for (int s=0;s<KNN;++s){ bd[s]=FLT_MAX; bi[s]=0; }
  for (int j=0;j<NP;++j){
    float4 fj = ((float4*)sf)[j];
    float dot = fi.x*fj.x + fi.y*fj.y + fi.z*fj.z + fi.w*fj.w;
    float d2 = (sqi + ssq[j]) - 2.0f*dot;
    if (d2 < bd[KNN-1]){
      float dk=d2; int ik=j;
      #pragma unroll
      for (int s=0;s<KNN;++s){
        bool sw = dk < bd[s];
        float td=bd[s]; int ti=bi[s];
        bd[s]=sw?dk:td; bi[s]=sw?ik:ti;
        dk=sw?td:dk;    ik=sw?ti:ik;
      }
    }
  }
  int n = b*NP + il;
  #pragma unroll
  for (int s=0;s<KNN;++s) idx1[n*KNN+s]=bi[s];
}

// ---------------- edgeconv1 (8->64->64->64, sum over K), LDS weights ----------------
__global__ __launch_bounds__(256,2) void edgeconv1_kernel(
    const float* __restrict__ xx, const int* __restrict__ idx1,
    const float* __restrict__ watg, const float* __restrict__ b1a,
    const float* __restrict__ wbtg, const float* __restrict__ b1b,
    const float* __restrict__ wctg, const float* __restrict__ b1c,
    float* __restrict__ x1, float* __restrict__ sq2){
  __shared__ alignas(16) float sf[NP*4];     // 16 KB points
  __shared__ alignas(16) float swa[512];     //  2 KB w1a^T [o][c]
  __shared__ alignas(16) float swb[4096];    // 16 KB w1b^T
  __shared__ alignas(16) float swc[4096];    // 16 KB w1c^T
  __shared__ float sba[64], sbb[64], sbc[64];
  int b = blockIdx.x >> 2;
  int q = blockIdx.x & 3;
  int t = threadIdx.x;
  const float4* base = (const float4*)(xx + (size_t)b*NP*4);
  for (int i = t; i < NP; i += 256) ((float4*)sf)[i] = base[i];
  for (int i = t; i < 128;  i += 256) ((float4*)swa)[i] = ((const float4*)watg)[i];
  for (int i = t; i < 1024; i += 256) ((float4*)swb)[i] = ((const float4*)wbtg)[i];
  for (int i = t; i < 1024; i += 256) ((float4*)swc)[i] = ((const float4*)wctg)[i];
  if (t < 64){ sba[t]=b1a[t]; sbb[t]=b1b[t]; sbc[t]=b1c[t]; }
  __syncthreads();
  int il = q*256 + t;
  int n = b*NP + il;
  float4 fi = ((float4*)sf)[il];
  float acc[64];
  #pragma unroll
  for (int o=0;o<64;++o) acc[o]=0.0f;
  #pragma unroll 1
  for (int k=0;k<KNN;++k){
    int j = idx1[n*KNN+k];
    float4 fj = ((float4*)sf)[j];
    float e[8];
    e[0]=fi.x; e[1]=fi.y; e[2]=fi.z; e[3]=fi.w;
    e[4]=fj.x-fi.x; e[5]=fj.y-fi.y; e[6]=fj.z-fi.z; e[7]=fj.w-fi.w;
    float h1[64];
    #pragma unroll
    for (int o=0;o<64;++o){
      float s = sba[o];
      float4 w0 = *(const float4*)&swa[o*8];
      float4 w1 = *(const float4*)&swa[o*8+4];
      s = fmaf(e[0],w0.x,s); s = fmaf(e[1],w0.y,s);
      s = fmaf(e[2],w0.z,s); s = fmaf(e[3],w0.w,s);
      s = fmaf(e[4],w1.x,s); s = fmaf(e[5],w1.y,s);
      s = fmaf(e[6],w1.z,s); s = fmaf(e[7],w1.w,s);
      h1[o] = lrelu(s);
    }
    float h2[64];
    #pragma unroll
    for (int o=0;o<64;++o){
      float s = sbb[o];
      #pragma unroll
      for (int c=0;c<64;c+=4){
        float4 w = *(const float4*)&swb[o*64+c];
        s = fmaf(h1[c+0],w.x,s); s = fmaf(h1[c+1],w.y,s);
        s = fmaf(h1[c+2],w.z,s); s = fmaf(h1[c+3],w.w,s);
      }
      h2[o] = lrelu(s);
    }
    #pragma unroll
    for (int o=0;o<64;++o){
      float s = sbc[o];
      #pragma unroll
      for (int c=0;c<64;c+=4){
        float4 w = *(const float4*)&swc[o*64+c];
        s = fmaf(h2[c+0],w.x,s); s = fmaf(h2[c+1],w.y,s);
        s = fmaf(h2[c+2],w.z,s); s = fmaf(h2[c+3],w.w,s);
      }
      acc[o] += lrelu(s);
    }
  }
  float s = 0.0f;
  #pragma unroll
  for (int o=0;o<64;++o){
    x1[(size_t)n*64+o] = acc[o];
    s = fmaf(acc[o], acc[o], s);
  }
  sq2[n] = s;
}

// ---------------- knn on 64-dim features, 2 points/thread ----------------
__global__ __launch_bounds__(128,2) void knn2_kernel(const float* __restrict__ x1,
                                                     const float* __restrict__ sq2,
                                                     int* __restrict__ idx2){
  __shared__ alignas(16) float sj[128*64];   // 32 KB
  __shared__ float ssq[128];
  int b = blockIdx.x >> 2, qq = blockIdx.x & 3;
  int t = threadIdx.x;
  int i0 = qq*256 + t, i1 = i0 + 128;
  int n0 = b*NP + i0, n1 = b*NP + i1;
  float xi0[64], xi1[64];
  #pragma unroll
  for (int c=0;c<64;c+=4){
    float4 v = *(const float4*)&x1[(size_t)n0*64+c];
    xi0[c]=v.x; xi0[c+1]=v.y; xi0[c+2]=v.z; xi0[c+3]=v.w;
    float4 w = *(const float4*)&x1[(size_t)n1*64+c];
    xi1[c]=w.x; xi1[c+1]=w.y; xi1[c+2]=w.z; xi1[c+3]=w.w;
  }
  float sqi0 = sq2[n0], sqi1 = sq2[n1];
  float bd0[KNN], bd1[KNN]; int bi0[KNN], bi1[KNN];
  #pragma unroll
  for (int s=0;s<KNN;++s){ bd0[s]=FLT_MAX; bi0[s]=0; bd1[s]=FLT_MAX; bi1[s]=0; }
  for (int tile=0; tile<8; ++tile){
    __syncthreads();
    const float4* src = (const float4*)(x1 + ((size_t)b*NP + tile*128)*64);
    for (int u=t; u<128*16; u+=128) ((float4*)sj)[u] = src[u];
    ssq[t] = sq2[b*NP + tile*128 + t];
    __syncthreads();
    #pragma unroll 1
    for (int j=0;j<128;++j){
      float dot0=0.0f, dot1=0.0f;
      #pragma unroll
      for (int c=0;c<64;c+=4){
        float4 v = *(const float4*)&sj[j*64+c];
        dot0 = fmaf(xi0[c+0],v.x,dot0); dot0 = fmaf(xi0[c+1],v.y,dot0);
        dot0 = fmaf(xi0[c+2],v.z,dot0); dot0 = fmaf(xi0[c+3],v.w,dot0);
        dot1 = fmaf(xi1[c+0],v.x,dot1); dot1 = fmaf(xi1[c+1],v.y,dot1);
        dot1 = fmaf(xi1[c+2],v.z,dot1); dot1 = fmaf(xi1[c+3],v.w,dot1);
      }
      int jg = tile*128 + j;
      float d0 = (sqi0 + ssq[j]) - 2.0f*dot0;
      if (d0 < bd0[KNN-1]){
        float dk=d0; int ik=jg;
        #pragma unroll
        for (int s=0;s<KNN;++s){
          bool sw = dk < bd0[s];
          float td=bd0[s]; int ti=bi0[s];
          bd0[s]=sw?dk:td; bi0[s]=sw?ik:ti;
          dk=sw?td:dk;     ik=sw?ti:ik;
        }
      }
      float d1 = (sqi1 + ssq[j]) - 2.0f*dot1;
      if (d1 < bd1[KNN-1]){
        float dk=d1; int ik=jg;
        #pragma unroll
        for (int s=0;s<KNN;++s){
          bool sw = dk < bd1[s];
          float td=bd1[s]; int ti=bi1[s];
          bd1[s]=sw?dk:td; bi1[s]=sw?ik:ti;
          dk=sw?td:dk;     ik=sw?ti:ik;
        }
      }
    }
  }
  #pragma unroll
  for (int s=0;s<KNN;++s){ idx2[n0*KNN+s]=bi0[s]; idx2[n1*KNN+s]=bi1[s]; }
}

// ---------------- q/r GEMM for edgeconv2: q=x1*Wbot, r=x1*(Wtop-Wbot)+b ----------------
__global__ __launch_bounds__(256,2) void qr2_kernel(const float* __restrict__ x1,
    const float* __restrict__ wcombg, const float* __restrict__ b2,
    float* __restrict__ q2, float* __restrict__ r2){
  __shared__ alignas(16) float sw[16384];    // 64 KB
  __shared__ float sb2[128];
  int t = threadIdx.x;
  for (int u=t; u<4096; u+=256) ((float4*)sw)[u] = ((const float4*)wcombg)[u];
  if (t < 128) sb2[t] = b2[t];
  __syncthreads();
  int n = blockIdx.x*256 + t;
  float xi[64];
  #pragma unroll
  for (int c=0;c<64;c+=4){
    float4 v = *(const float4*)&x1[(size_t)n*64+c];
    xi[c]=v.x; xi[c+1]=v.y; xi[c+2]=v.z; xi[c+3]=v.w;
  }
  #pragma unroll 1
  for (int op=0; op<128; op+=4){
    float q0=0,q1=0,q2a=0,q3=0, r0,r1,r2a,r3;
    r0=sb2[op]; r1=sb2[op+1]; r2a=sb2[op+2]; r3=sb2[op+3];
    #pragma unroll
    for (int c=0;c<64;c+=4){
      float4 a0 = *(const float4*)&sw[(op+0)*64+c];
      float4 a1 = *(const float4*)&sw[(op+1)*64+c];
      float4 a2 = *(const float4*)&sw[(op+2)*64+c];
      float4 a3 = *(const float4*)&sw[(op+3)*64+c];
      float4 c0 = *(const float4*)&sw[(128+op+0)*64+c];
      float4 c1 = *(const float4*)&sw[(128+op+1)*64+c];
      float4 c2 = *(const float4*)&sw[(128+op+2)*64+c];
      float4 c3 = *(const float4*)&sw[(128+op+3)*64+c];
      q0=fmaf(xi[c],a0.x,q0); q0=fmaf(xi[c+1],a0.y,q0); q0=fmaf(xi[c+2],a0.z,q0); q0=fmaf(xi[c+3],a0.w,q0);
      q1=fmaf(xi[c],a1.x,q1); q1=fmaf(xi[c+1],a1.y,q1); q1=fmaf(xi[c+2],a1.z,q1); q1=fmaf(xi[c+3],a1.w,q1);
      q2a=fmaf(xi[c],a2.x,q2a); q2a=fmaf(xi[c+1],a2.y,q2a); q2a=fmaf(xi[c+2],a2.z,q2a); q2a=fmaf(xi[c+3],a2.w,q2a);
      q3=fmaf(xi[c],a3.x,q3); q3=fmaf(xi[c+1],a3.y,q3); q3=fmaf(xi[c+2],a3.z,q3); q3=fmaf(xi[c+3],a3.w,q3);
      r0=fmaf(xi[c],c0.x,r0); r0=fmaf(xi[c+1],c0.y,r0); r0=fmaf(xi[c+2],c0.z,r0); r0=fmaf(xi[c+3],c0.w,r0);
      r1=fmaf(xi[c],c1.x,r1); r1=fmaf(xi[c+1],c1.y,r1); r1=fmaf(xi[c+2],c1.z,r1); r1=fmaf(xi[c+3],c1.w,r1);
      r2a=fmaf(xi[c],c2.x,r2a); r2a=fmaf(xi[c+1],c2.y,r2a); r2a=fmaf(xi[c+2],c2.z,r2a); r2a=fmaf(xi[c+3],c2.w,r2a);
      r3=fmaf(xi[c],c3.x,r3); r3=fmaf(xi[c+1],c3.y,r3); r3=fmaf(xi[c+2],c3.z,r3); r3=fmaf(xi[c+3],c3.w,r3);
    }
    float4 qv; qv.x=q0; qv.y=q1; qv.z=q2a; qv.w=q3;
    float4 rv; rv.x=r0; rv.y=r1; rv.z=r2a; rv.w=r3;
    *(float4*)&q2[(size_t)n*128+op] = qv;
    *(float4*)&r2[(size_t)n*128+op] = rv;
  }
}

// ---------------- edgeconv2 gather + fused mean (never materialize x2) ----------------
__global__ __launch_bounds__(256,4) void ec2_gather_kernel(
    const float* __restrict__ q2, const float* __restrict__ r2,
    const int* __restrict__ idx2, float* __restrict__ fmean){
  __shared__ alignas(16) float4 red[256];
  int t = threadIdx.x;
  int b = blockIdx.x >> 7, blk = blockIdx.x & 127;
  int p = t >> 5, c4 = t & 31;
  int n = b*NP + blk*8 + p;
  float4 r = *(const float4*)&r2[(size_t)n*128 + c4*4];
  float4 acc; acc.x=0; acc.y=0; acc.z=0; acc.w=0;
  #pragma unroll 1
  for (int k=0;k<KNN;++k){
    int j = idx2[n*KNN+k];
    float4 qv = *(const float4*)&q2[((size_t)b*NP + j)*128 + c4*4];
    acc.x += lrelu(r.x+qv.x);
    acc.y += lrelu(r.y+qv.y);
    acc.z += lrelu(r.z+qv.z);
    acc.w += lrelu(r.w+qv.w);
  }
  red[t] = acc;
  __syncthreads();
  if (t < 128){ float4 o = red[t+128]; red[t].x+=o.x; red[t].y+=o.y; red[t].z+=o.z; red[t].w+=o.w; }
  __syncthreads();
  if (t < 64){ float4 o = red[t+64]; red[t].x+=o.x; red[t].y+=o.y; red[t].z+=o.z; red[t].w+=o.w; }
  __syncthreads();
  if (t < 32){
    float4 s = red[t]; float4 o = red[t+32];
    s.x+=o.x; s.y+=o.y; s.z+=o.z; s.w+=o.w;
    float* dst = &fmean[b*192 + 64 + c4*4];
    atomicAdd(dst+0, s.x); atomicAdd(dst+1, s.y);
    atomicAdd(dst+2, s.z); atomicAdd(dst+3, s.w);
  }
}

// ---------------- mean of x1 -> fmean[:,0:64] (sums; /1024 applied in head) ----------------
__global__ __launch_bounds__(256,4) void mean1_kernel(const float* __restrict__ x1,
                                                      float* __restrict__ fmean){
  __shared__ float red[256];
  int t = threadIdx.x;
  int b = blockIdx.x >> 2, qq = blockIdx.x & 3;
  int c = t & 63, pl = t >> 6;
  float s = 0.0f;
  for (int i=0;i<64;++i){
    int p = qq*256 + pl + 4*i;
    s += x1[((size_t)b*NP + p)*64 + c];
  }
  red[t] = s;
  __syncthreads();
  if (t < 128) red[t] += red[t+128];
  __syncthreads();
  if (t < 64) atomicAdd(&fmean[b*192 + c], red[t] + red[t+64]);
}

// ---------------- head (192->1024->512->256->3) ----------------
__global__ __launch_bounds__(256) void head_kernel(
    const float* __restrict__ fmean,
    const float* __restrict__ wl,  const float* __restrict__ bl,
    const float* __restrict__ wm1, const float* __restrict__ bm1,
    const float* __restrict__ wm2, const float* __restrict__ bm2,
    const float* __restrict__ wm3, const float* __restrict__ bm3,
    float* __restrict__ out){
  __shared__ float v0[192];
  __shared__ float o1[1024];
  __shared__ float h1[512];
  __shared__ float h2[256];
  int b = blockIdx.x, t = threadIdx.x;
  if (t < 192) v0[t] = fmean[b*192 + t] * (1.0f/1024.0f);
  __syncthreads();
  #pragma unroll
  for (int r=0;r<4;++r){
    int o = r*256 + t;
    float s = bl[o];
    #pragma unroll 8
    for (int c=0;c<192;++c) s = fmaf(v0[c], wl[c*1024 + o], s);
    o1[o] = s;
  }
  __syncthreads();
  #pragma unroll
  for (int r=0;r<2;++r){
    int o = r*256 + t;
    float s = bm1[o];
    #pragma unroll 8
    for (int c=0;c<1024;++c) s = fmaf(o1[c], wm1[c*512 + o], s);
    h1[o] = lrelu(s);
  }
  __syncthreads();
  {
    int o = t;
    float s = bm2[o];
    #pragma unroll 8
    for (int c=0;c<512;++c) s = fmaf(h1[c], wm2[c*256 + o], s);
    h2[o] = lrelu(s);
  }
  __syncthreads();
  if (t < 3){
    float s = bm3[t];
    #pragma unroll 8
    for (int c=0;c<256;++c) s = fmaf(h2[c], wm3[c*3 + t], s);
    out[b*3 + t] = s;
  }
}

extern "C" void kernel_launch(void* const* d_in, const int* in_sizes, int n_in,
                              void* d_out, int out_size, void* d_ws, size_t ws_size,
                              hipStream_t stream) {
  const float* x   = (const float*)d_in[0];
  const float* pos = (const float*)d_in[1];
  const float* w1a = (const float*)d_in[3];
  const float* b1a = (const float*)d_in[4];
  const float* w1b = (const float*)d_in[5];
  const float* b1b = (const float*)d_in[6];
  const float* w1c = (const float*)d_in[7];
  const float* b1c = (const float*)d_in[8];
  const float* w2  = (const float*)d_in[9];
  const float* b2  = (const float*)d_in[10];
  const float* wl  = (const float*)d_in[11];
  const float* bl  = (const float*)d_in[12];
  const float* wm1 = (const float*)d_in[13];
  const float* bm1 = (const float*)d_in[14];
  const float* wm2 = (const float*)d_in[15];
  const float* bm2 = (const float*)d_in[16];
  const float* wm3 = (const float*)d_in[17];
  const float* bm3 = (const float*)d_in[18];
  float* out = (float*)d_out;

  float* ws_f  = (float*)d_ws;
  float* xx    = ws_f;                    // 262144 f
  float* x1    = xx + 262144;             // 4194304 f (16 MB)
  float* sq2   = x1 + 4194304;            // 65536 f
  int*   idx1  = (int*)(sq2 + 65536);     // 655360 i
  int*   idx2  = idx1 + 655360;           // 655360 i
  float* q2    = (float*)(idx2 + 655360); // 8388608 f (32 MB)
  float* r2    = q2 + 8388608;            // 8388608 f (32 MB)
  float* wat   = r2 + 8388608;            // 512 f
  float* wbt   = wat + 512;               // 4096 f
  float* wct   = wbt + 4096;              // 4096 f
  float* wcomb = wct + 4096;              // 16384 f
  float* fmean = wcomb + 16384;           // 12288 f

  zero_fmean<<<48, 256, 0, stream>>>(fmean);
  prep1_kernel<<<34, 256, 0, stream>>>(w1a, w1b, w1c, wat, wbt, wct);
  prep2_kernel<<<64, 256, 0, stream>>>(w2, wcomb);
  build_xx<<<256, 256, 0, stream>>>(x, pos, xx);
  knn1_kernel<<<256, 256, 0, stream>>>(xx, idx1);
  edgeconv1_kernel<<<256, 256, 0, stream>>>(xx, idx1, wat, b1a, wbt, b1b, wct, b1c, x1, sq2);
  knn2_kernel<<<256, 128, 0, stream>>>(x1, sq2, idx2);
  qr2_kernel<<<256, 256, 0, stream>>>(x1, wcomb, b2, q2, r2);
  ec2_gather_kernel<<<8192, 256, 0, stream>>>(q2, r2, idx2, fmean);
  mean1_kernel<<<256, 256, 0, stream>>>(x1, fmean);
  head_kernel<<<NB, 256, 0, stream>>>(fmean, wl, bl, wm1, bm1, wm2, bm2, wm3, bm3, out);
}

// Round 3
// 16176.138 us; speedup vs baseline: 1.0638x; 1.0638x over previous
//
#include <hip/hip_runtime.h>
#include <float.h>

#define NB 64
#define NP 1024
#define KNN 10

__device__ __forceinline__ float lrelu(float v){ return v >= 0.0f ? v : 0.01f*v; }

// ---------------- zero fmean (harness poisons ws each launch) ----------------
__global__ void zero_fmean(float* __restrict__ f){
  int i = blockIdx.x*256 + threadIdx.x;
  if (i < NB*192) f[i] = 0.0f;
}

// ---------------- prep: transpose small weights ----------------
// wat[o*8+c]=w1a[c*64+o]; wbt[o*64+c]=w1b[c*64+o]; wct[o*64+c]=w1c[c*64+o]
__global__ void prep1_kernel(const float* __restrict__ w1a, const float* __restrict__ w1b,
                             const float* __restrict__ w1c,
                             float* __restrict__ wat, float* __restrict__ wbt,
                             float* __restrict__ wct){
  int tid = blockIdx.x*256 + threadIdx.x;
  if (tid < 512){
    int o = tid >> 3, c = tid & 7;
    wat[tid] = w1a[c*64 + o];
  } else if (tid < 4608){
    int i = tid - 512; int o = i >> 6, c = i & 63;
    wbt[i] = w1b[c*64 + o];
  } else if (tid < 8704){
    int i = tid - 4608; int o = i >> 6, c = i & 63;
    wct[i] = w1c[c*64 + o];
  }
}

// wcomb[op*64+c]: op<128 -> W_bot[c][op] = w2[(64+c)*128+op]
//                 op>=128 -> (W_top - W_bot)[c][op-128]
__global__ void prep2_kernel(const float* __restrict__ w2, float* __restrict__ wcomb){
  int tid = blockIdx.x*256 + threadIdx.x;  // 16384
  int op = tid >> 6, c = tid & 63;
  if (op < 128){
    wcomb[tid] = w2[(64+c)*128 + op];
  } else {
    int o = op - 128;
    wcomb[tid] = w2[c*128 + o] - w2[(64+c)*128 + o];
  }
}

// ---------------- build xx = concat(x, pos) ----------------
__global__ void build_xx(const float* __restrict__ x, const float* __restrict__ pos,
                         float* __restrict__ xx){
  int n = blockIdx.x*256 + threadIdx.x;
  float4 v;
  v.x = x[n];
  v.y = pos[3*n+0];
  v.z = pos[3*n+1];
  v.w = pos[3*n+2];
  ((float4*)xx)[n] = v;
}

// ---------------- knn on 4-dim features ----------------
__global__ __launch_bounds__(256,4) void knn1_kernel(const float* __restrict__ xx,
                                                     int* __restrict__ idx1){
  __shared__ alignas(16) float sf[NP*4];
  __shared__ float ssq[NP];
  int b = blockIdx.x >> 2;
  int q = blockIdx.x & 3;
  const float4* base = (const float4*)(xx + (size_t)b*NP*4);
  for (int t = threadIdx.x; t < NP; t += 256){
    float4 v = base[t];
    ((float4*)sf)[t] = v;
    ssq[t] = ((v.x*v.x + v.y*v.y) + v.z*v.z) + v.w*v.w;
  }
  __syncthreads();
  int il = q*256 + threadIdx.x;
  float4 fi = ((float4*)sf)[il];
  float sqi = ssq[il];
  float bd[KNN]; int bi[KNN];
  #pragma unroll
  for (int s=0;s<KNN;++s){ bd[s]=FLT_MAX; bi[s]=0; }
  for (int j=0;j<NP;++j){
    float4 fj = ((float4*)sf)[j];
    float dot = fi.x*fj.x + fi.y*fj.y + fi.z*fj.z + fi.w*fj.w;
    float d2 = (sqi + ssq[j]) - 2.0f*dot;
    if (d2 < bd[KNN-1]){
      float dk=d2; int ik=j;
      #pragma unroll
      for (int s=0;s<KNN;++s){
        bool sw = dk < bd[s];
        float td=bd[s]; int ti=bi[s];
        bd[s]=sw?dk:td; bi[s]=sw?ik:ti;
        dk=sw?td:dk;    ik=sw?ti:ik;
      }
    }
  }
  int n = b*NP + il;
  #pragma unroll
  for (int s=0;s<KNN;++s) idx1[n*KNN+s]=bi[s];
}

// ---------------- edgeconv1 (8->64->64->64, sum over K), LDS weights ----------------
// NOTE: (256,1) — live set is ~200 VGPRs (h1+h2+acc); capping lower spills to
// scratch (R2: 12.3 GB FETCH_SIZE, VALUBusy 0.6%). Occupancy follows actual
// VGPR count, so the loose bound still gives 2 waves/SIMD.
__global__ __launch_bounds__(256,1) void edgeconv1_kernel(
    const float* __restrict__ xx, const int* __restrict__ idx1,
    const float* __restrict__ watg, const float* __restrict__ b1a,
    const float* __restrict__ wbtg, const float* __restrict__ b1b,
    const float* __restrict__ wctg, const float* __restrict__ b1c,
    float* __restrict__ x1, float* __restrict__ sq2){
  __shared__ alignas(16) float sf[NP*4];     // 16 KB points
  __shared__ alignas(16) float swa[512];     //  2 KB w1a^T [o][c]
  __shared__ alignas(16) float swb[4096];    // 16 KB w1b^T
  __shared__ alignas(16) float swc[4096];    // 16 KB w1c^T
  __shared__ float sba[64], sbb[64], sbc[64];
  int b = blockIdx.x >> 2;
  int q = blockIdx.x & 3;
  int t = threadIdx.x;
  const float4* base = (const float4*)(xx + (size_t)b*NP*4);
  for (int i = t; i < NP; i += 256) ((float4*)sf)[i] = base[i];
  for (int i = t; i < 128;  i += 256) ((float4*)swa)[i] = ((const float4*)watg)[i];
  for (int i = t; i < 1024; i += 256) ((float4*)swb)[i] = ((const float4*)wbtg)[i];
  for (int i = t; i < 1024; i += 256) ((float4*)swc)[i] = ((const float4*)wctg)[i];
  if (t < 64){ sba[t]=b1a[t]; sbb[t]=b1b[t]; sbc[t]=b1c[t]; }
  __syncthreads();
  int il = q*256 + t;
  int n = b*NP + il;
  float4 fi = ((float4*)sf)[il];
  float acc[64];
  #pragma unroll
  for (int o=0;o<64;++o) acc[o]=0.0f;
  #pragma unroll 1
  for (int k=0;k<KNN;++k){
    int j = idx1[n*KNN+k];
    float4 fj = ((float4*)sf)[j];
    float e[8];
    e[0]=fi.x; e[1]=fi.y; e[2]=fi.z; e[3]=fi.w;
    e[4]=fj.x-fi.x; e[5]=fj.y-fi.y; e[6]=fj.z-fi.z; e[7]=fj.w-fi.w;
    float h1[64];
    #pragma unroll
    for (int o=0;o<64;++o){
      float s = sba[o];
      float4 w0 = *(const float4*)&swa[o*8];
      float4 w1 = *(const float4*)&swa[o*8+4];
      s = fmaf(e[0],w0.x,s); s = fmaf(e[1],w0.y,s);
      s = fmaf(e[2],w0.z,s); s = fmaf(e[3],w0.w,s);
      s = fmaf(e[4],w1.x,s); s = fmaf(e[5],w1.y,s);
      s = fmaf(e[6],w1.z,s); s = fmaf(e[7],w1.w,s);
      h1[o] = lrelu(s);
    }
    float h2[64];
    #pragma unroll
    for (int o=0;o<64;++o){
      float s = sbb[o];
      #pragma unroll
      for (int c=0;c<64;c+=4){
        float4 w = *(const float4*)&swb[o*64+c];
        s = fmaf(h1[c+0],w.x,s); s = fmaf(h1[c+1],w.y,s);
        s = fmaf(h1[c+2],w.z,s); s = fmaf(h1[c+3],w.w,s);
      }
      h2[o] = lrelu(s);
    }
    #pragma unroll
    for (int o=0;o<64;++o){
      float s = sbc[o];
      #pragma unroll
      for (int c=0;c<64;c+=4){
        float4 w = *(const float4*)&swc[o*64+c];
        s = fmaf(h2[c+0],w.x,s); s = fmaf(h2[c+1],w.y,s);
        s = fmaf(h2[c+2],w.z,s); s = fmaf(h2[c+3],w.w,s);
      }
      acc[o] += lrelu(s);
    }
  }
  float s = 0.0f;
  #pragma unroll
  for (int o=0;o<64;++o){
    x1[(size_t)n*64+o] = acc[o];
    s = fmaf(acc[o], acc[o], s);
  }
  sq2[n] = s;
}

// ---------------- knn on 64-dim features, 2 points/thread ----------------
__global__ __launch_bounds__(128,1) void knn2_kernel(const float* __restrict__ x1,
                                                     const float* __restrict__ sq2,
                                                     int* __restrict__ idx2){
  __shared__ alignas(16) float sj[128*64];   // 32 KB
  __shared__ float ssq[128];
  int b = blockIdx.x >> 2, qq = blockIdx.x & 3;
  int t = threadIdx.x;
  int i0 = qq*256 + t, i1 = i0 + 128;
  int n0 = b*NP + i0, n1 = b*NP + i1;
  float xi0[64], xi1[64];
  #pragma unroll
  for (int c=0;c<64;c+=4){
    float4 v = *(const float4*)&x1[(size_t)n0*64+c];
    xi0[c]=v.x; xi0[c+1]=v.y; xi0[c+2]=v.z; xi0[c+3]=v.w;
    float4 w = *(const float4*)&x1[(size_t)n1*64+c];
    xi1[c]=w.x; xi1[c+1]=w.y; xi1[c+2]=w.z; xi1[c+3]=w.w;
  }
  float sqi0 = sq2[n0], sqi1 = sq2[n1];
  float bd0[KNN], bd1[KNN]; int bi0[KNN], bi1[KNN];
  #pragma unroll
  for (int s=0;s<KNN;++s){ bd0[s]=FLT_MAX; bi0[s]=0; bd1[s]=FLT_MAX; bi1[s]=0; }
  for (int tile=0; tile<8; ++tile){
    __syncthreads();
    const float4* src = (const float4*)(x1 + ((size_t)b*NP + tile*128)*64);
    for (int u=t; u<128*16; u+=128) ((float4*)sj)[u] = src[u];
    ssq[t] = sq2[b*NP + tile*128 + t];
    __syncthreads();
    #pragma unroll 1
    for (int j=0;j<128;++j){
      float dot0=0.0f, dot1=0.0f;
      #pragma unroll
      for (int c=0;c<64;c+=4){
        float4 v = *(const float4*)&sj[j*64+c];
        dot0 = fmaf(xi0[c+0],v.x,dot0); dot0 = fmaf(xi0[c+1],v.y,dot0);
        dot0 = fmaf(xi0[c+2],v.z,dot0); dot0 = fmaf(xi0[c+3],v.w,dot0);
        dot1 = fmaf(xi1[c+0],v.x,dot1); dot1 = fmaf(xi1[c+1],v.y,dot1);
        dot1 = fmaf(xi1[c+2],v.z,dot1); dot1 = fmaf(xi1[c+3],v.w,dot1);
      }
      int jg = tile*128 + j;
      float d0 = (sqi0 + ssq[j]) - 2.0f*dot0;
      if (d0 < bd0[KNN-1]){
        float dk=d0; int ik=jg;
        #pragma unroll
        for (int s=0;s<KNN;++s){
          bool sw = dk < bd0[s];
          float td=bd0[s]; int ti=bi0[s];
          bd0[s]=sw?dk:td; bi0[s]=sw?ik:ti;
          dk=sw?td:dk;     ik=sw?ti:ik;
        }
      }
      float d1 = (sqi1 + ssq[j]) - 2.0f*dot1;
      if (d1 < bd1[KNN-1]){
        float dk=d1; int ik=jg;
        #pragma unroll
        for (int s=0;s<KNN;++s){
          bool sw = dk < bd1[s];
          float td=bd1[s]; int ti=bi1[s];
          bd1[s]=sw?dk:td; bi1[s]=sw?ik:ti;
          dk=sw?td:dk;     ik=sw?ti:ik;
        }
      }
    }
  }
  #pragma unroll
  for (int s=0;s<KNN;++s){ idx2[n0*KNN+s]=bi0[s]; idx2[n1*KNN+s]=bi1[s]; }
}

// ---------------- q/r GEMM for edgeconv2: q=x1*Wbot, r=x1*(Wtop-Wbot)+b ----------------
__global__ __launch_bounds__(256,1) void qr2_kernel(const float* __restrict__ x1,
    const float* __restrict__ wcombg, const float* __restrict__ b2,
    float* __restrict__ q2, float* __restrict__ r2){
  __shared__ alignas(16) float sw[16384];    // 64 KB
  __shared__ float sb2[128];
  int t = threadIdx.x;
  for (int u=t; u<4096; u+=256) ((float4*)sw)[u] = ((const float4*)wcombg)[u];
  if (t < 128) sb2[t] = b2[t];
  __syncthreads();
  int n = blockIdx.x*256 + t;
  float xi[64];
  #pragma unroll
  for (int c=0;c<64;c+=4){
    float4 v = *(const float4*)&x1[(size_t)n*64+c];
    xi[c]=v.x; xi[c+1]=v.y; xi[c+2]=v.z; xi[c+3]=v.w;
  }
  #pragma unroll 1
  for (int op=0; op<128; op+=4){
    float q0=0,q1=0,q2a=0,q3=0, r0,r1,r2a,r3;
    r0=sb2[op]; r1=sb2[op+1]; r2a=sb2[op+2]; r3=sb2[op+3];
    #pragma unroll
    for (int c=0;c<64;c+=4){
      float4 a0 = *(const float4*)&sw[(op+0)*64+c];
      float4 a1 = *(const float4*)&sw[(op+1)*64+c];
      float4 a2 = *(const float4*)&sw[(op+2)*64+c];
      float4 a3 = *(const float4*)&sw[(op+3)*64+c];
      float4 c0 = *(const float4*)&sw[(128+op+0)*64+c];
      float4 c1 = *(const float4*)&sw[(128+op+1)*64+c];
      float4 c2 = *(const float4*)&sw[(128+op+2)*64+c];
      float4 c3 = *(const float4*)&sw[(128+op+3)*64+c];
      q0=fmaf(xi[c],a0.x,q0); q0=fmaf(xi[c+1],a0.y,q0); q0=fmaf(xi[c+2],a0.z,q0); q0=fmaf(xi[c+3],a0.w,q0);
      q1=fmaf(xi[c],a1.x,q1); q1=fmaf(xi[c+1],a1.y,q1); q1=fmaf(xi[c+2],a1.z,q1); q1=fmaf(xi[c+3],a1.w,q1);
      q2a=fmaf(xi[c],a2.x,q2a); q2a=fmaf(xi[c+1],a2.y,q2a); q2a=fmaf(xi[c+2],a2.z,q2a); q2a=fmaf(xi[c+3],a2.w,q2a);
      q3=fmaf(xi[c],a3.x,q3); q3=fmaf(xi[c+1],a3.y,q3); q3=fmaf(xi[c+2],a3.z,q3); q3=fmaf(xi[c+3],a3.w,q3);
      r0=fmaf(xi[c],c0.x,r0); r0=fmaf(xi[c+1],c0.y,r0); r0=fmaf(xi[c+2],c0.z,r0); r0=fmaf(xi[c+3],c0.w,r0);
      r1=fmaf(xi[c],c1.x,r1); r1=fmaf(xi[c+1],c1.y,r1); r1=fmaf(xi[c+2],c1.z,r1); r1=fmaf(xi[c+3],c1.w,r1);
      r2a=fmaf(xi[c],c2.x,r2a); r2a=fmaf(xi[c+1],c2.y,r2a); r2a=fmaf(xi[c+2],c2.z,r2a); r2a=fmaf(xi[c+3],c2.w,r2a);
      r3=fmaf(xi[c],c3.x,r3); r3=fmaf(xi[c+1],c3.y,r3); r3=fmaf(xi[c+2],c3.z,r3); r3=fmaf(xi[c+3],c3.w,r3);
    }
    float4 qv; qv.x=q0; qv.y=q1; qv.z=q2a; qv.w=q3;
    float4 rv; rv.x=r0; rv.y=r1; rv.z=r2a; rv.w=r3;
    *(float4*)&q2[(size_t)n*128+op] = qv;
    *(float4*)&r2[(size_t)n*128+op] = rv;
  }
}

// ---------------- edgeconv2 gather + fused mean (never materialize x2) ----------------
__global__ __launch_bounds__(256,4) void ec2_gather_kernel(
    const float* __restrict__ q2, const float* __restrict__ r2,
    const int* __restrict__ idx2, float* __restrict__ fmean){
  __shared__ alignas(16) float4 red[256];
  int t = threadIdx.x;
  int b = blockIdx.x >> 7, blk = blockIdx.x & 127;
  int p = t >> 5, c4 = t & 31;
  int n = b*NP + blk*8 + p;
  float4 r = *(const float4*)&r2[(size_t)n*128 + c4*4];
  float4 acc; acc.x=0; acc.y=0; acc.z=0; acc.w=0;
  #pragma unroll 1
  for (int k=0;k<KNN;++k){
    int j = idx2[n*KNN+k];
    float4 qv = *(const float4*)&q2[((size_t)b*NP + j)*128 + c4*4];
    acc.x += lrelu(r.x+qv.x);
    acc.y += lrelu(r.y+qv.y);
    acc.z += lrelu(r.z+qv.z);
    acc.w += lrelu(r.w+qv.w);
  }
  red[t] = acc;
  __syncthreads();
  if (t < 128){ float4 o = red[t+128]; red[t].x+=o.x; red[t].y+=o.y; red[t].z+=o.z; red[t].w+=o.w; }
  __syncthreads();
  if (t < 64){ float4 o = red[t+64]; red[t].x+=o.x; red[t].y+=o.y; red[t].z+=o.z; red[t].w+=o.w; }
  __syncthreads();
  if (t < 32){
    float4 s = red[t]; float4 o = red[t+32];
    s.x+=o.x; s.y+=o.y; s.z+=o.z; s.w+=o.w;
    float* dst = &fmean[b*192 + 64 + c4*4];
    atomicAdd(dst+0, s.x); atomicAdd(dst+1, s.y);
    atomicAdd(dst+2, s.z); atomicAdd(dst+3, s.w);
  }
}

// ---------------- mean of x1 -> fmean[:,0:64] (sums; /1024 applied in head) ----------------
__global__ __launch_bounds__(256,4) void mean1_kernel(const float* __restrict__ x1,
                                                      float* __restrict__ fmean){
  __shared__ float red[256];
  int t = threadIdx.x;
  int b = blockIdx.x >> 2, qq = blockIdx.x & 3;
  int c = t & 63, pl = t >> 6;
  float s = 0.0f;
  for (int i=0;i<64;++i){
    int p = qq*256 + pl + 4*i;
    s += x1[((size_t)b*NP + p)*64 + c];
  }
  red[t] = s;
  __syncthreads();
  if (t < 128) red[t] += red[t+128];
  __syncthreads();
  if (t < 64) atomicAdd(&fmean[b*192 + c], red[t] + red[t+64]);
}

// ---------------- head (192->1024->512->256->3) ----------------
__global__ __launch_bounds__(256) void head_kernel(
    const float* __restrict__ fmean,
    const float* __restrict__ wl,  const float* __restrict__ bl,
    const float* __restrict__ wm1, const float* __restrict__ bm1,
    const float* __restrict__ wm2, const float* __restrict__ bm2,
    const float* __restrict__ wm3, const float* __restrict__ bm3,
    float* __restrict__ out){
  __shared__ float v0[192];
  __shared__ float o1[1024];
  __shared__ float h1[512];
  __shared__ float h2[256];
  int b = blockIdx.x, t = threadIdx.x;
  if (t < 192) v0[t] = fmean[b*192 + t] * (1.0f/1024.0f);
  __syncthreads();
  #pragma unroll
  for (int r=0;r<4;++r){
    int o = r*256 + t;
    float s = bl[o];
    #pragma unroll 8
    for (int c=0;c<192;++c) s = fmaf(v0[c], wl[c*1024 + o], s);
    o1[o] = s;
  }
  __syncthreads();
  #pragma unroll
  for (int r=0;r<2;++r){
    int o = r*256 + t;
    float s = bm1[o];
    #pragma unroll 8
    for (int c=0;c<1024;++c) s = fmaf(o1[c], wm1[c*512 + o], s);
    h1[o] = lrelu(s);
  }
  __syncthreads();
  {
    int o = t;
    float s = bm2[o];
    #pragma unroll 8
    for (int c=0;c<512;++c) s = fmaf(h1[c], wm2[c*256 + o], s);
    h2[o] = lrelu(s);
  }
  __syncthreads();
  if (t < 3){
    float s = bm3[t];
    #pragma unroll 8
    for (int c=0;c<256;++c) s = fmaf(h2[c], wm3[c*3 + t], s);
    out[b*3 + t] = s;
  }
}

extern "C" void kernel_launch(void* const* d_in, const int* in_sizes, int n_in,
                              void* d_out, int out_size, void* d_ws, size_t ws_size,
                              hipStream_t stream) {
  const float* x   = (const float*)d_in[0];
  const float* pos = (const float*)d_in[1];
  const float* w1a = (const float*)d_in[3];
  const float* b1a = (const float*)d_in[4];
  const float* w1b = (const float*)d_in[5];
  const float* b1b = (const float*)d_in[6];
  const float* w1c = (const float*)d_in[7];
  const float* b1c = (const float*)d_in[8];
  const float* w2  = (const float*)d_in[9];
  const float* b2  = (const float*)d_in[10];
  const float* wl  = (const float*)d_in[11];
  const float* bl  = (const float*)d_in[12];
  const float* wm1 = (const float*)d_in[13];
  const float* bm1 = (const float*)d_in[14];
  const float* wm2 = (const float*)d_in[15];
  const float* bm2 = (const float*)d_in[16];
  const float* wm3 = (const float*)d_in[17];
  const float* bm3 = (const float*)d_in[18];
  float* out = (float*)d_out;

  float* ws_f  = (float*)d_ws;
  float* xx    = ws_f;                    // 262144 f
  float* x1    = xx + 262144;             // 4194304 f (16 MB)
  float* sq2   = x1 + 4194304;            // 65536 f
  int*   idx1  = (int*)(sq2 + 65536);     // 655360 i
  int*   idx2  = idx1 + 655360;           // 655360 i
  float* q2    = (float*)(idx2 + 655360); // 8388608 f (32 MB)
  float* r2    = q2 + 8388608;            // 8388608 f (32 MB)
  float* wat   = r2 + 8388608;            // 512 f
  float* wbt   = wat + 512;               // 4096 f
  float* wct   = wbt + 4096;              // 4096 f
  float* wcomb = wct + 4096;              // 16384 f
  float* fmean = wcomb + 16384;           // 12288 f

  zero_fmean<<<48, 256, 0, stream>>>(fmean);
  prep1_kernel<<<34, 256, 0, stream>>>(w1a, w1b, w1c, wat, wbt, wct);
  prep2_kernel<<<64, 256, 0, stream>>>(w2, wcomb);
  build_xx<<<256, 256, 0, stream>>>(x, pos, xx);
  knn1_kernel<<<256, 256, 0, stream>>>(xx, idx1);
  edgeconv1_kernel<<<256, 256, 0, stream>>>(xx, idx1, wat, b1a, wbt, b1b, wct, b1c, x1, sq2);
  knn2_kernel<<<256, 128, 0, stream>>>(x1, sq2, idx2);
  qr2_kernel<<<256, 256, 0, stream>>>(x1, wcomb, b2, q2, r2);
  ec2_gather_kernel<<<8192, 256, 0, stream>>>(q2, r2, idx2, fmean);
  mean1_kernel<<<256, 256, 0, stream>>>(x1, fmean);
  head_kernel<<<NB, 256, 0, stream>>>(fmean, wl, bl, wm1, bm1, wm2, bm2, wm3, bm3, out);
}

// Round 4
// 1399.477 us; speedup vs baseline: 12.2960x; 11.5587x over previous
//
#include <hip/hip_runtime.h>
#include <float.h>

#define NB 64
#define NP 1024
#define KNN 10

__device__ __forceinline__ float lrelu(float v){ return v >= 0.0f ? v : 0.01f*v; }

// ---------------- zero fmean (harness poisons ws each launch) ----------------
__global__ void zero_fmean(float* __restrict__ f){
  int i = blockIdx.x*256 + threadIdx.x;
  if (i < NB*192) f[i] = 0.0f;
}

// wcomb[op*64+c]: op<128 -> W_bot[c][op] = w2[(64+c)*128+op]
//                 op>=128 -> (W_top - W_bot)[c][op-128]
__global__ void prep2_kernel(const float* __restrict__ w2, float* __restrict__ wcomb){
  int tid = blockIdx.x*256 + threadIdx.x;  // 16384
  int op = tid >> 6, c = tid & 63;
  if (op < 128){
    wcomb[tid] = w2[(64+c)*128 + op];
  } else {
    int o = op - 128;
    wcomb[tid] = w2[c*128 + o] - w2[(64+c)*128 + o];
  }
}

// ---------------- build xx = concat(x, pos) ----------------
__global__ void build_xx(const float* __restrict__ x, const float* __restrict__ pos,
                         float* __restrict__ xx){
  int n = blockIdx.x*256 + threadIdx.x;
  float4 v;
  v.x = x[n];
  v.y = pos[3*n+0];
  v.z = pos[3*n+1];
  v.w = pos[3*n+2];
  ((float4*)xx)[n] = v;
}

// ---------------- knn on 4-dim features ----------------
__global__ __launch_bounds__(256,4) void knn1_kernel(const float* __restrict__ xx,
                                                     int* __restrict__ idx1){
  __shared__ alignas(16) float sf[NP*4];
  __shared__ float ssq[NP];
  int b = blockIdx.x >> 2;
  int q = blockIdx.x & 3;
  const float4* base = (const float4*)(xx + (size_t)b*NP*4);
  for (int t = threadIdx.x; t < NP; t += 256){
    float4 v = base[t];
    ((float4*)sf)[t] = v;
    ssq[t] = ((v.x*v.x + v.y*v.y) + v.z*v.z) + v.w*v.w;
  }
  __syncthreads();
  int il = q*256 + threadIdx.x;
  float4 fi = ((float4*)sf)[il];
  float sqi = ssq[il];
  float bd[KNN]; int bi[KNN];
  #pragma unroll
  for (int s=0;s<KNN;++s){ bd[s]=FLT_MAX; bi[s]=0; }
  for (int j=0;j<NP;++j){
    float4 fj = ((float4*)sf)[j];
    float dot = fi.x*fj.x + fi.y*fj.y + fi.z*fj.z + fi.w*fj.w;
    float d2 = (sqi + ssq[j]) - 2.0f*dot;
    if (d2 < bd[KNN-1]){
      float dk=d2; int ik=j;
      #pragma unroll
      for (int s=0;s<KNN;++s){
        bool sw = dk < bd[s];
        float td=bd[s]; int ti=bi[s];
        bd[s]=sw?dk:td; bi[s]=sw?ik:ti;
        dk=sw?td:dk;    ik=sw?ti:ik;
      }
    }
  }
  int n = b*NP + il;
  #pragma unroll
  for (int s=0;s<KNN;++s) idx1[n*KNN+s]=bi[s];
}

// ---------------- edgeconv1: 2 threads per point, 32 outputs each ----------------
// Live set per thread ~120 VGPRs (acc32+pr32+h2v32+e8) — avoids the 256-VGPR
// spill cliff that killed the 1-thread-per-point LDS-weight versions (R2/R3).
// Full-width activations exchanged through a per-point LDS row (stride 65:
// (65p+c)%32 = (p+c)%32 -> conflict-free; pair reads broadcast).
__global__ __launch_bounds__(256,2) void edgeconv1_kernel(
    const float* __restrict__ xx, const int* __restrict__ idx1,
    const float* __restrict__ w1a, const float* __restrict__ b1a,
    const float* __restrict__ w1b, const float* __restrict__ b1b,
    const float* __restrict__ w1c, const float* __restrict__ b1c,
    float* __restrict__ x1, float* __restrict__ sq2){
  __shared__ alignas(16) float swa[512];     //  2 KB w1a [c][o]
  __shared__ alignas(16) float swb[4096];    // 16 KB w1b [c][o]
  __shared__ alignas(16) float swc[4096];    // 16 KB w1c [c][o]
  __shared__ float sba[64], sbb[64], sbc[64];
  __shared__ float hx[128*65];               // 33.3 KB per-point activation rows
  int t = threadIdx.x;
  for (int i=t; i<128;  i+=256) ((float4*)swa)[i] = ((const float4*)w1a)[i];
  for (int i=t; i<1024; i+=256) ((float4*)swb)[i] = ((const float4*)w1b)[i];
  for (int i=t; i<1024; i+=256) ((float4*)swc)[i] = ((const float4*)w1c)[i];
  if (t < 64){ sba[t]=b1a[t]; sbb[t]=b1b[t]; sbc[t]=b1c[t]; }
  __syncthreads();

  int p  = t >> 1;          // local point 0..127
  int hf = t & 1;           // output half
  int ob = hf*32;
  int b  = blockIdx.x >> 3; // batch
  int g  = blockIdx.x & 7;  // point group
  int n  = b*NP + g*128 + p;
  float* hrow = &hx[p*65];

  float4 fi = ((const float4*)xx)[n];
  float acc[32];
  #pragma unroll
  for (int o=0;o<32;++o) acc[o]=0.0f;

  #pragma unroll 1
  for (int k=0;k<KNN;++k){
    int j = idx1[n*KNN+k];
    float4 fj = ((const float4*)xx)[b*NP + j];
    float e[8];
    e[0]=fi.x; e[1]=fi.y; e[2]=fi.z; e[3]=fi.w;
    e[4]=fj.x-fi.x; e[5]=fj.y-fi.y; e[6]=fj.z-fi.z; e[7]=fj.w-fi.w;

    // ---- layer a: 8 -> my 32 outputs -> LDS
    {
      float pr[32];
      #pragma unroll
      for (int o=0;o<32;++o) pr[o]=sba[ob+o];
      #pragma unroll
      for (int c=0;c<8;++c){
        #pragma unroll
        for (int o4=0;o4<8;++o4){
          float4 w = *(const float4*)&swa[c*64 + ob + o4*4];
          pr[o4*4+0]=fmaf(e[c],w.x,pr[o4*4+0]);
          pr[o4*4+1]=fmaf(e[c],w.y,pr[o4*4+1]);
          pr[o4*4+2]=fmaf(e[c],w.z,pr[o4*4+2]);
          pr[o4*4+3]=fmaf(e[c],w.w,pr[o4*4+3]);
        }
      }
      #pragma unroll
      for (int o=0;o<32;++o) hrow[ob+o] = lrelu(pr[o]);
    }
    __syncthreads();

    // ---- layer b: read full h1 row, compute my 32 h2 (keep in regs)
    float h2v[32];
    {
      float pr[32];
      #pragma unroll
      for (int o=0;o<32;++o) pr[o]=sbb[ob+o];
      #pragma unroll 4
      for (int c=0;c<64;++c){
        float hv = hrow[c];
        #pragma unroll
        for (int o4=0;o4<8;++o4){
          float4 w = *(const float4*)&swb[c*64 + ob + o4*4];
          pr[o4*4+0]=fmaf(hv,w.x,pr[o4*4+0]);
          pr[o4*4+1]=fmaf(hv,w.y,pr[o4*4+1]);
          pr[o4*4+2]=fmaf(hv,w.z,pr[o4*4+2]);
          pr[o4*4+3]=fmaf(hv,w.w,pr[o4*4+3]);
        }
      }
      #pragma unroll
      for (int o=0;o<32;++o) h2v[o] = lrelu(pr[o]);
    }
    __syncthreads();              // all h1 reads done before overwrite
    #pragma unroll
    for (int o=0;o<32;++o) hrow[ob+o] = h2v[o];
    __syncthreads();

    // ---- layer c: read full h2 row, accumulate my 32 outputs
    {
      float pr[32];
      #pragma unroll
      for (int o=0;o<32;++o) pr[o]=sbc[ob+o];
      #pragma unroll 4
      for (int c=0;c<64;++c){
        float hv = hrow[c];
        #pragma unroll
        for (int o4=0;o4<8;++o4){
          float4 w = *(const float4*)&swc[c*64 + ob + o4*4];
          pr[o4*4+0]=fmaf(hv,w.x,pr[o4*4+0]);
          pr[o4*4+1]=fmaf(hv,w.y,pr[o4*4+1]);
          pr[o4*4+2]=fmaf(hv,w.z,pr[o4*4+2]);
          pr[o4*4+3]=fmaf(hv,w.w,pr[o4*4+3]);
        }
      }
      #pragma unroll
      for (int o=0;o<32;++o) acc[o] += lrelu(pr[o]);
    }
    __syncthreads();
  }

  // write my half of x1; sq2 via pair exchange
  float s = 0.0f;
  #pragma unroll
  for (int o=0;o<32;o+=4){
    float4 v; v.x=acc[o]; v.y=acc[o+1]; v.z=acc[o+2]; v.w=acc[o+3];
    *(float4*)&x1[(size_t)n*64 + ob + o] = v;
    s = fmaf(acc[o],acc[o], fmaf(acc[o+1],acc[o+1], fmaf(acc[o+2],acc[o+2], fmaf(acc[o+3],acc[o+3], s))));
  }
  s += __shfl_xor(s, 1);
  if (hf == 0) sq2[n] = s;
}

// ---------------- knn on 64-dim features, 1 point/thread (R1 form, ~110 VGPR) ----------------
__global__ __launch_bounds__(256,2) void knn2_kernel(const float* __restrict__ x1,
                                                     const float* __restrict__ sq2,
                                                     int* __restrict__ idx2){
  __shared__ alignas(16) float sj[256*64];   // 64 KB
  __shared__ float ssq[256];
  int b = blockIdx.x >> 2;
  int q = blockIdx.x & 3;
  int t = threadIdx.x;
  int il = q*256 + t;
  int n = b*NP + il;
  float xi[64];
  #pragma unroll
  for (int c=0;c<64;c+=4){
    float4 v = *(const float4*)&x1[(size_t)n*64+c];
    xi[c]=v.x; xi[c+1]=v.y; xi[c+2]=v.z; xi[c+3]=v.w;
  }
  float sqi = sq2[n];
  float bd[KNN]; int bi[KNN];
  #pragma unroll
  for (int s=0;s<KNN;++s){ bd[s]=FLT_MAX; bi[s]=0; }
  for (int tile=0; tile<4; ++tile){
    __syncthreads();
    const float4* src = (const float4*)(x1 + ((size_t)b*NP + tile*256)*64);
    for (int u=t; u<256*16; u+=256) ((float4*)sj)[u] = src[u];
    ssq[t] = sq2[b*NP + tile*256 + t];
    __syncthreads();
    #pragma unroll 1
    for (int j=0;j<256;++j){
      float dot = 0.0f;
      #pragma unroll
      for (int c=0;c<64;c+=4){
        float4 v = *(const float4*)&sj[j*64+c];
        dot = fmaf(xi[c+0],v.x,dot); dot = fmaf(xi[c+1],v.y,dot);
        dot = fmaf(xi[c+2],v.z,dot); dot = fmaf(xi[c+3],v.w,dot);
      }
      float d2 = (sqi + ssq[j]) - 2.0f*dot;
      if (d2 < bd[KNN-1]){
        float dk=d2; int ik=tile*256+j;
        #pragma unroll
        for (int s=0;s<KNN;++s){
          bool sw = dk < bd[s];
          float td=bd[s]; int ti=bi[s];
          bd[s]=sw?dk:td; bi[s]=sw?ik:ti;
          dk=sw?td:dk;    ik=sw?ti:ik;
        }
      }
    }
  }
  #pragma unroll
  for (int s=0;s<KNN;++s) idx2[n*KNN+s]=bi[s];
}

// ---------------- q/r GEMM for edgeconv2: q=x1*Wbot, r=x1*(Wtop-Wbot)+b ----------------
__global__ __launch_bounds__(256,1) void qr2_kernel(const float* __restrict__ x1,
    const float* __restrict__ wcombg, const float* __restrict__ b2,
    float* __restrict__ q2, float* __restrict__ r2){
  __shared__ alignas(16) float sw[16384];    // 64 KB
  __shared__ float sb2[128];
  int t = threadIdx.x;
  for (int u=t; u<4096; u+=256) ((float4*)sw)[u] = ((const float4*)wcombg)[u];
  if (t < 128) sb2[t] = b2[t];
  __syncthreads();
  int n = blockIdx.x*256 + t;
  float xi[64];
  #pragma unroll
  for (int c=0;c<64;c+=4){
    float4 v = *(const float4*)&x1[(size_t)n*64+c];
    xi[c]=v.x; xi[c+1]=v.y; xi[c+2]=v.z; xi[c+3]=v.w;
  }
  #pragma unroll 1
  for (int op=0; op<128; op+=4){
    float q0=0,q1=0,q2a=0,q3=0, r0,r1,r2a,r3;
    r0=sb2[op]; r1=sb2[op+1]; r2a=sb2[op+2]; r3=sb2[op+3];
    #pragma unroll
    for (int c=0;c<64;c+=4){
      float4 a0 = *(const float4*)&sw[(op+0)*64+c];
      float4 a1 = *(const float4*)&sw[(op+1)*64+c];
      float4 a2 = *(const float4*)&sw[(op+2)*64+c];
      float4 a3 = *(const float4*)&sw[(op+3)*64+c];
      float4 c0 = *(const float4*)&sw[(128+op+0)*64+c];
      float4 c1 = *(const float4*)&sw[(128+op+1)*64+c];
      float4 c2 = *(const float4*)&sw[(128+op+2)*64+c];
      float4 c3 = *(const float4*)&sw[(128+op+3)*64+c];
      q0=fmaf(xi[c],a0.x,q0); q0=fmaf(xi[c+1],a0.y,q0); q0=fmaf(xi[c+2],a0.z,q0); q0=fmaf(xi[c+3],a0.w,q0);
      q1=fmaf(xi[c],a1.x,q1); q1=fmaf(xi[c+1],a1.y,q1); q1=fmaf(xi[c+2],a1.z,q1); q1=fmaf(xi[c+3],a1.w,q1);
      q2a=fmaf(xi[c],a2.x,q2a); q2a=fmaf(xi[c+1],a2.y,q2a); q2a=fmaf(xi[c+2],a2.z,q2a); q2a=fmaf(xi[c+3],a2.w,q2a);
      q3=fmaf(xi[c],a3.x,q3); q3=fmaf(xi[c+1],a3.y,q3); q3=fmaf(xi[c+2],a3.z,q3); q3=fmaf(xi[c+3],a3.w,q3);
      r0=fmaf(xi[c],c0.x,r0); r0=fmaf(xi[c+1],c0.y,r0); r0=fmaf(xi[c+2],c0.z,r0); r0=fmaf(xi[c+3],c0.w,r0);
      r1=fmaf(xi[c],c1.x,r1); r1=fmaf(xi[c+1],c1.y,r1); r1=fmaf(xi[c+2],c1.z,r1); r1=fmaf(xi[c+3],c1.w,r1);
      r2a=fmaf(xi[c],c2.x,r2a); r2a=fmaf(xi[c+1],c2.y,r2a); r2a=fmaf(xi[c+2],c2.z,r2a); r2a=fmaf(xi[c+3],c2.w,r2a);
      r3=fmaf(xi[c],c3.x,r3); r3=fmaf(xi[c+1],c3.y,r3); r3=fmaf(xi[c+2],c3.z,r3); r3=fmaf(xi[c+3],c3.w,r3);
    }
    float4 qv; qv.x=q0; qv.y=q1; qv.z=q2a; qv.w=q3;
    float4 rv; rv.x=r0; rv.y=r1; rv.z=r2a; rv.w=r3;
    *(float4*)&q2[(size_t)n*128+op] = qv;
    *(float4*)&r2[(size_t)n*128+op] = rv;
  }
}

// ---------------- edgeconv2 gather + fused mean (never materialize x2) ----------------
__global__ __launch_bounds__(256,4) void ec2_gather_kernel(
    const float* __restrict__ q2, const float* __restrict__ r2,
    const int* __restrict__ idx2, float* __restrict__ fmean){
  __shared__ alignas(16) float4 red[256];
  int t = threadIdx.x;
  int b = blockIdx.x >> 7, blk = blockIdx.x & 127;
  int p = t >> 5, c4 = t & 31;
  int n = b*NP + blk*8 + p;
  float4 r = *(const float4*)&r2[(size_t)n*128 + c4*4];
  float4 acc; acc.x=0; acc.y=0; acc.z=0; acc.w=0;
  #pragma unroll 1
  for (int k=0;k<KNN;++k){
    int j = idx2[n*KNN+k];
    float4 qv = *(const float4*)&q2[((size_t)b*NP + j)*128 + c4*4];
    acc.x += lrelu(r.x+qv.x);
    acc.y += lrelu(r.y+qv.y);
    acc.z += lrelu(r.z+qv.z);
    acc.w += lrelu(r.w+qv.w);
  }
  red[t] = acc;
  __syncthreads();
  if (t < 128){ float4 o = red[t+128]; red[t].x+=o.x; red[t].y+=o.y; red[t].z+=o.z; red[t].w+=o.w; }
  __syncthreads();
  if (t < 64){ float4 o = red[t+64]; red[t].x+=o.x; red[t].y+=o.y; red[t].z+=o.z; red[t].w+=o.w; }
  __syncthreads();
  if (t < 32){
    float4 s = red[t]; float4 o = red[t+32];
    s.x+=o.x; s.y+=o.y; s.z+=o.z; s.w+=o.w;
    float* dst = &fmean[b*192 + 64 + c4*4];
    atomicAdd(dst+0, s.x); atomicAdd(dst+1, s.y);
    atomicAdd(dst+2, s.z); atomicAdd(dst+3, s.w);
  }
}

// ---------------- mean of x1 -> fmean[:,0:64] (sums; /1024 applied in head) ----------------
__global__ __launch_bounds__(256,4) void mean1_kernel(const float* __restrict__ x1,
                                                      float* __restrict__ fmean){
  __shared__ float red[256];
  int t = threadIdx.x;
  int b = blockIdx.x >> 2, qq = blockIdx.x & 3;
  int c = t & 63, pl = t >> 6;
  float s = 0.0f;
  for (int i=0;i<64;++i){
    int p = qq*256 + pl + 4*i;
    s += x1[((size_t)b*NP + p)*64 + c];
  }
  red[t] = s;
  __syncthreads();
  if (t < 128) red[t] += red[t+128];
  __syncthreads();
  if (t < 64) atomicAdd(&fmean[b*192 + c], red[t] + red[t+64]);
}

// ---------------- head (192->1024->512->256->3) ----------------
__global__ __launch_bounds__(256) void head_kernel(
    const float* __restrict__ fmean,
    const float* __restrict__ wl,  const float* __restrict__ bl,
    const float* __restrict__ wm1, const float* __restrict__ bm1,
    const float* __restrict__ wm2, const float* __restrict__ bm2,
    const float* __restrict__ wm3, const float* __restrict__ bm3,
    float* __restrict__ out){
  __shared__ float v0[192];
  __shared__ float o1[1024];
  __shared__ float h1[512];
  __shared__ float h2[256];
  int b = blockIdx.x, t = threadIdx.x;
  if (t < 192) v0[t] = fmean[b*192 + t] * (1.0f/1024.0f);
  __syncthreads();
  #pragma unroll
  for (int r=0;r<4;++r){
    int o = r*256 + t;
    float s = bl[o];
    #pragma unroll 8
    for (int c=0;c<192;++c) s = fmaf(v0[c], wl[c*1024 + o], s);
    o1[o] = s;
  }
  __syncthreads();
  #pragma unroll
  for (int r=0;r<2;++r){
    int o = r*256 + t;
    float s = bm1[o];
    #pragma unroll 8
    for (int c=0;c<1024;++c) s = fmaf(o1[c], wm1[c*512 + o], s);
    h1[o] = lrelu(s);
  }
  __syncthreads();
  {
    int o = t;
    float s = bm2[o];
    #pragma unroll 8
    for (int c=0;c<512;++c) s = fmaf(h1[c], wm2[c*256 + o], s);
    h2[o] = lrelu(s);
  }
  __syncthreads();
  if (t < 3){
    float s = bm3[t];
    #pragma unroll 8
    for (int c=0;c<256;++c) s = fmaf(h2[c], wm3[c*3 + t], s);
    out[b*3 + t] = s;
  }
}

extern "C" void kernel_launch(void* const* d_in, const int* in_sizes, int n_in,
                              void* d_out, int out_size, void* d_ws, size_t ws_size,
                              hipStream_t stream) {
  const float* x   = (const float*)d_in[0];
  const float* pos = (const float*)d_in[1];
  const float* w1a = (const float*)d_in[3];
  const float* b1a = (const float*)d_in[4];
  const float* w1b = (const float*)d_in[5];
  const float* b1b = (const float*)d_in[6];
  const float* w1c = (const float*)d_in[7];
  const float* b1c = (const float*)d_in[8];
  const float* w2  = (const float*)d_in[9];
  const float* b2  = (const float*)d_in[10];
  const float* wl  = (const float*)d_in[11];
  const float* bl  = (const float*)d_in[12];
  const float* wm1 = (const float*)d_in[13];
  const float* bm1 = (const float*)d_in[14];
  const float* wm2 = (const float*)d_in[15];
  const float* bm2 = (const float*)d_in[16];
  const float* wm3 = (const float*)d_in[17];
  const float* bm3 = (const float*)d_in[18];
  float* out = (float*)d_out;

  float* ws_f  = (float*)d_ws;
  float* xx    = ws_f;                    // 262144 f
  float* x1    = xx + 262144;             // 4194304 f (16 MB)
  float* sq2   = x1 + 4194304;            // 65536 f
  int*   idx1  = (int*)(sq2 + 65536);     // 655360 i
  int*   idx2  = idx1 + 655360;           // 655360 i
  float* q2    = (float*)(idx2 + 655360); // 8388608 f (32 MB)
  float* r2    = q2 + 8388608;            // 8388608 f (32 MB)
  float* wcomb = r2 + 8388608;            // 16384 f
  float* fmean = wcomb + 16384;           // 12288 f

  zero_fmean<<<48, 256, 0, stream>>>(fmean);
  prep2_kernel<<<64, 256, 0, stream>>>(w2, wcomb);
  build_xx<<<256, 256, 0, stream>>>(x, pos, xx);
  knn1_kernel<<<256, 256, 0, stream>>>(xx, idx1);
  edgeconv1_kernel<<<512, 256, 0, stream>>>(xx, idx1, w1a, b1a, w1b, b1b, w1c, b1c, x1, sq2);
  knn2_kernel<<<256, 256, 0, stream>>>(x1, sq2, idx2);
  qr2_kernel<<<256, 256, 0, stream>>>(x1, wcomb, b2, q2, r2);
  ec2_gather_kernel<<<8192, 256, 0, stream>>>(q2, r2, idx2, fmean);
  mean1_kernel<<<256, 256, 0, stream>>>(x1, fmean);
  head_kernel<<<NB, 256, 0, stream>>>(fmean, wl, bl, wm1, bm1, wm2, bm2, wm3, bm3, out);
}

// Round 5
// 1232.162 us; speedup vs baseline: 13.9656x; 1.1358x over previous
//
#include <hip/hip_runtime.h>
#include <float.h>

#define NB 64
#define NP 1024
#define KNN 10

__device__ __forceinline__ float lrelu(float v){ return v >= 0.0f ? v : 0.01f*v; }

// ---------------- zero fmean (harness poisons ws each launch) ----------------
__global__ void zero_fmean(float* __restrict__ f){
  int i = blockIdx.x*256 + threadIdx.x;
  if (i < NB*192) f[i] = 0.0f;
}

// wcomb[op*64+c]: op<128 -> W_bot[c][op] = w2[(64+c)*128+op]
//                 op>=128 -> (W_top - W_bot)[c][op-128]
__global__ void prep2_kernel(const float* __restrict__ w2, float* __restrict__ wcomb){
  int tid = blockIdx.x*256 + threadIdx.x;  // 16384
  int op = tid >> 6, c = tid & 63;
  if (op < 128){
    wcomb[tid] = w2[(64+c)*128 + op];
  } else {
    int o = op - 128;
    wcomb[tid] = w2[c*128 + o] - w2[(64+c)*128 + o];
  }
}

// ---------------- build xx = concat(x, pos) ----------------
__global__ void build_xx(const float* __restrict__ x, const float* __restrict__ pos,
                         float* __restrict__ xx){
  int n = blockIdx.x*256 + threadIdx.x;
  float4 v;
  v.x = x[n];
  v.y = pos[3*n+0];
  v.z = pos[3*n+1];
  v.w = pos[3*n+2];
  ((float4*)xx)[n] = v;
}

// ---------------- knn on 4-dim features ----------------
__global__ __launch_bounds__(256,4) void knn1_kernel(const float* __restrict__ xx,
                                                     int* __restrict__ idx1){
  __shared__ alignas(16) float sf[NP*4];
  __shared__ float ssq[NP];
  int b = blockIdx.x >> 2;
  int q = blockIdx.x & 3;
  const float4* base = (const float4*)(xx + (size_t)b*NP*4);
  for (int t = threadIdx.x; t < NP; t += 256){
    float4 v = base[t];
    ((float4*)sf)[t] = v;
    ssq[t] = ((v.x*v.x + v.y*v.y) + v.z*v.z) + v.w*v.w;
  }
  __syncthreads();
  int il = q*256 + threadIdx.x;
  float4 fi = ((float4*)sf)[il];
  float sqi = ssq[il];
  float bd[KNN]; int bi[KNN];
  #pragma unroll
  for (int s=0;s<KNN;++s){ bd[s]=FLT_MAX; bi[s]=0; }
  for (int j=0;j<NP;++j){
    float4 fj = ((float4*)sf)[j];
    float dot = fi.x*fj.x + fi.y*fj.y + fi.z*fj.z + fi.w*fj.w;
    float d2 = (sqi + ssq[j]) - 2.0f*dot;
    if (d2 < bd[KNN-1]){
      float dk=d2; int ik=j;
      #pragma unroll
      for (int s=0;s<KNN;++s){
        bool sw = dk < bd[s];
        float td=bd[s]; int ti=bi[s];
        bd[s]=sw?dk:td; bi[s]=sw?ik:ti;
        dk=sw?td:dk;    ik=sw?ti:ik;
      }
    }
  }
  int n = b*NP + il;
  #pragma unroll
  for (int s=0;s<KNN;++s) idx1[n*KNN+s]=bi[s];
}

// ---------------- edgeconv1: 2 threads per point, 32 outputs each ----------------
__global__ __launch_bounds__(256,2) void edgeconv1_kernel(
    const float* __restrict__ xx, const int* __restrict__ idx1,
    const float* __restrict__ w1a, const float* __restrict__ b1a,
    const float* __restrict__ w1b, const float* __restrict__ b1b,
    const float* __restrict__ w1c, const float* __restrict__ b1c,
    float* __restrict__ x1, float* __restrict__ sq2){
  __shared__ alignas(16) float swa[512];     //  2 KB w1a [c][o]
  __shared__ alignas(16) float swb[4096];    // 16 KB w1b [c][o]
  __shared__ alignas(16) float swc[4096];    // 16 KB w1c [c][o]
  __shared__ float sba[64], sbb[64], sbc[64];
  __shared__ float hx[128*65];               // 33.3 KB per-point activation rows
  int t = threadIdx.x;
  for (int i=t; i<128;  i+=256) ((float4*)swa)[i] = ((const float4*)w1a)[i];
  for (int i=t; i<1024; i+=256) ((float4*)swb)[i] = ((const float4*)w1b)[i];
  for (int i=t; i<1024; i+=256) ((float4*)swc)[i] = ((const float4*)w1c)[i];
  if (t < 64){ sba[t]=b1a[t]; sbb[t]=b1b[t]; sbc[t]=b1c[t]; }
  __syncthreads();

  int p  = t >> 1;          // local point 0..127
  int hf = t & 1;           // output half
  int ob = hf*32;
  int b  = blockIdx.x >> 3; // batch
  int g  = blockIdx.x & 7;  // point group
  int n  = b*NP + g*128 + p;
  float* hrow = &hx[p*65];

  float4 fi = ((const float4*)xx)[n];
  float acc[32];
  #pragma unroll
  for (int o=0;o<32;++o) acc[o]=0.0f;

  #pragma unroll 1
  for (int k=0;k<KNN;++k){
    int j = idx1[n*KNN+k];
    float4 fj = ((const float4*)xx)[b*NP + j];
    float e[8];
    e[0]=fi.x; e[1]=fi.y; e[2]=fi.z; e[3]=fi.w;
    e[4]=fj.x-fi.x; e[5]=fj.y-fi.y; e[6]=fj.z-fi.z; e[7]=fj.w-fi.w;

    // ---- layer a: 8 -> my 32 outputs -> LDS
    {
      float pr[32];
      #pragma unroll
      for (int o=0;o<32;++o) pr[o]=sba[ob+o];
      #pragma unroll
      for (int c=0;c<8;++c){
        #pragma unroll
        for (int o4=0;o4<8;++o4){
          float4 w = *(const float4*)&swa[c*64 + ob + o4*4];
          pr[o4*4+0]=fmaf(e[c],w.x,pr[o4*4+0]);
          pr[o4*4+1]=fmaf(e[c],w.y,pr[o4*4+1]);
          pr[o4*4+2]=fmaf(e[c],w.z,pr[o4*4+2]);
          pr[o4*4+3]=fmaf(e[c],w.w,pr[o4*4+3]);
        }
      }
      #pragma unroll
      for (int o=0;o<32;++o) hrow[ob+o] = lrelu(pr[o]);
    }
    __syncthreads();

    // ---- layer b: read full h1 row, compute my 32 h2 (keep in regs)
    float h2v[32];
    {
      float pr[32];
      #pragma unroll
      for (int o=0;o<32;++o) pr[o]=sbb[ob+o];
      #pragma unroll 4
      for (int c=0;c<64;++c){
        float hv = hrow[c];
        #pragma unroll
        for (int o4=0;o4<8;++o4){
          float4 w = *(const float4*)&swb[c*64 + ob + o4*4];
          pr[o4*4+0]=fmaf(hv,w.x,pr[o4*4+0]);
          pr[o4*4+1]=fmaf(hv,w.y,pr[o4*4+1]);
          pr[o4*4+2]=fmaf(hv,w.z,pr[o4*4+2]);
          pr[o4*4+3]=fmaf(hv,w.w,pr[o4*4+3]);
        }
      }
      #pragma unroll
      for (int o=0;o<32;++o) h2v[o] = lrelu(pr[o]);
    }
    __syncthreads();              // all h1 reads done before overwrite
    #pragma unroll
    for (int o=0;o<32;++o) hrow[ob+o] = h2v[o];
    __syncthreads();

    // ---- layer c: read full h2 row, accumulate my 32 outputs
    {
      float pr[32];
      #pragma unroll
      for (int o=0;o<32;++o) pr[o]=sbc[ob+o];
      #pragma unroll 4
      for (int c=0;c<64;++c){
        float hv = hrow[c];
        #pragma unroll
        for (int o4=0;o4<8;++o4){
          float4 w = *(const float4*)&swc[c*64 + ob + o4*4];
          pr[o4*4+0]=fmaf(hv,w.x,pr[o4*4+0]);
          pr[o4*4+1]=fmaf(hv,w.y,pr[o4*4+1]);
          pr[o4*4+2]=fmaf(hv,w.z,pr[o4*4+2]);
          pr[o4*4+3]=fmaf(hv,w.w,pr[o4*4+3]);
        }
      }
      #pragma unroll
      for (int o=0;o<32;++o) acc[o] += lrelu(pr[o]);
    }
    __syncthreads();
  }

  float s = 0.0f;
  #pragma unroll
  for (int o=0;o<32;o+=4){
    float4 v; v.x=acc[o]; v.y=acc[o+1]; v.z=acc[o+2]; v.w=acc[o+3];
    *(float4*)&x1[(size_t)n*64 + ob + o] = v;
    s = fmaf(acc[o],acc[o], fmaf(acc[o+1],acc[o+1], fmaf(acc[o+2],acc[o+2], fmaf(acc[o+3],acc[o+3], s))));
  }
  s += __shfl_xor(s, 1);
  if (hf == 0) sq2[n] = s;
}

// ---------------- knn2: 2 points/thread, half j-range per block ----------------
// grid 256 = 64 b x 2 point-halves x 2 j-halves. Each block: 512 i-pts, 512 j's.
// 32 KB j-tile (128 pts) -> LDS reads amortized over 2 points/thread.
// Emits per-half sorted top-10 (d,idx) for a later merge.
__global__ __launch_bounds__(256,1) void knn2_kernel(const float* __restrict__ x1,
                                                     const float* __restrict__ sq2,
                                                     float* __restrict__ bdh,
                                                     int* __restrict__ bih){
  __shared__ alignas(16) float sj[128*64];   // 32 KB
  __shared__ float ssq[128];
  int bid = blockIdx.x;
  int b  = bid >> 2;
  int q  = (bid >> 1) & 1;  // point half
  int jh = bid & 1;         // j half
  int t = threadIdx.x;
  int i0 = q*512 + t;
  int i1 = i0 + 256;
  int n0 = b*NP + i0, n1 = b*NP + i1;
  float xi0[64], xi1[64];
  #pragma unroll
  for (int c=0;c<64;c+=4){
    float4 v = *(const float4*)&x1[(size_t)n0*64+c];
    xi0[c]=v.x; xi0[c+1]=v.y; xi0[c+2]=v.z; xi0[c+3]=v.w;
    float4 w = *(const float4*)&x1[(size_t)n1*64+c];
    xi1[c]=w.x; xi1[c+1]=w.y; xi1[c+2]=w.z; xi1[c+3]=w.w;
  }
  float sqi0 = sq2[n0], sqi1 = sq2[n1];
  float bd0[KNN], bd1[KNN]; int bi0[KNN], bi1[KNN];
  #pragma unroll
  for (int s=0;s<KNN;++s){ bd0[s]=FLT_MAX; bi0[s]=0; bd1[s]=FLT_MAX; bi1[s]=0; }
  for (int tile=0; tile<4; ++tile){
    __syncthreads();
    const float4* src = (const float4*)(x1 + ((size_t)b*NP + jh*512 + tile*128)*64);
    for (int u=t; u<2048; u+=256) ((float4*)sj)[u] = src[u];
    if (t < 128) ssq[t] = sq2[b*NP + jh*512 + tile*128 + t];
    __syncthreads();
    #pragma unroll 1
    for (int j=0;j<128;++j){
      float dot0=0.0f, dot1=0.0f;
      #pragma unroll
      for (int c=0;c<64;c+=4){
        float4 v = *(const float4*)&sj[j*64+c];
        dot0 = fmaf(xi0[c+0],v.x,dot0); dot0 = fmaf(xi0[c+1],v.y,dot0);
        dot0 = fmaf(xi0[c+2],v.z,dot0); dot0 = fmaf(xi0[c+3],v.w,dot0);
        dot1 = fmaf(xi1[c+0],v.x,dot1); dot1 = fmaf(xi1[c+1],v.y,dot1);
        dot1 = fmaf(xi1[c+2],v.z,dot1); dot1 = fmaf(xi1[c+3],v.w,dot1);
      }
      int jg = jh*512 + tile*128 + j;
      float sq_j = ssq[j];
      float d0 = (sqi0 + sq_j) - 2.0f*dot0;
      if (d0 < bd0[KNN-1]){
        float dk=d0; int ik=jg;
        #pragma unroll
        for (int s=0;s<KNN;++s){
          bool sw = dk < bd0[s];
          float td=bd0[s]; int ti=bi0[s];
          bd0[s]=sw?dk:td; bi0[s]=sw?ik:ti;
          dk=sw?td:dk;     ik=sw?ti:ik;
        }
      }
      float d1 = (sqi1 + sq_j) - 2.0f*dot1;
      if (d1 < bd1[KNN-1]){
        float dk=d1; int ik=jg;
        #pragma unroll
        for (int s=0;s<KNN;++s){
          bool sw = dk < bd1[s];
          float td=bd1[s]; int ti=bi1[s];
          bd1[s]=sw?dk:td; bi1[s]=sw?ik:ti;
          dk=sw?td:dk;     ik=sw?ti:ik;
        }
      }
    }
  }
  #pragma unroll
  for (int s=0;s<KNN;++s){
    bdh[((size_t)n0*2 + jh)*KNN + s] = bd0[s];
    bih[((size_t)n0*2 + jh)*KNN + s] = bi0[s];
    bdh[((size_t)n1*2 + jh)*KNN + s] = bd1[s];
    bih[((size_t)n1*2 + jh)*KNN + s] = bi1[s];
  }
}

// merge two sorted half-lists; tie -> list0 (lower j indices), matching top_k
__global__ void knn2_merge(const float* __restrict__ bdh, const int* __restrict__ bih,
                           int* __restrict__ idx2){
  int n = blockIdx.x*256 + threadIdx.x;
  const float* d = &bdh[(size_t)n*2*KNN];
  const int*   iv = &bih[(size_t)n*2*KNN];
  int p0=0, p1=0;
  #pragma unroll
  for (int s=0;s<KNN;++s){
    float a = d[p0], bb = d[KNN+p1];
    bool take0 = (a <= bb);
    idx2[(size_t)n*KNN+s] = take0 ? iv[p0] : iv[KNN+p1];
    p0 += take0; p1 += !take0;
  }
}

// ---------------- q/r GEMM for edgeconv2: q=x1*Wbot, r=x1*(Wtop-Wbot)+b ----------------
__global__ __launch_bounds__(256,1) void qr2_kernel(const float* __restrict__ x1,
    const float* __restrict__ wcombg, const float* __restrict__ b2,
    float* __restrict__ q2, float* __restrict__ r2){
  __shared__ alignas(16) float sw[16384];    // 64 KB
  __shared__ float sb2[128];
  int t = threadIdx.x;
  for (int u=t; u<4096; u+=256) ((float4*)sw)[u] = ((const float4*)wcombg)[u];
  if (t < 128) sb2[t] = b2[t];
  __syncthreads();
  int n = blockIdx.x*256 + t;
  float xi[64];
  #pragma unroll
  for (int c=0;c<64;c+=4){
    float4 v = *(const float4*)&x1[(size_t)n*64+c];
    xi[c]=v.x; xi[c+1]=v.y; xi[c+2]=v.z; xi[c+3]=v.w;
  }
  #pragma unroll 1
  for (int op=0; op<128; op+=4){
    float q0=0,q1=0,q2a=0,q3=0, r0,r1,r2a,r3;
    r0=sb2[op]; r1=sb2[op+1]; r2a=sb2[op+2]; r3=sb2[op+3];
    #pragma unroll
    for (int c=0;c<64;c+=4){
      float4 a0 = *(const float4*)&sw[(op+0)*64+c];
      float4 a1 = *(const float4*)&sw[(op+1)*64+c];
      float4 a2 = *(const float4*)&sw[(op+2)*64+c];
      float4 a3 = *(const float4*)&sw[(op+3)*64+c];
      float4 c0 = *(const float4*)&sw[(128+op+0)*64+c];
      float4 c1 = *(const float4*)&sw[(128+op+1)*64+c];
      float4 c2 = *(const float4*)&sw[(128+op+2)*64+c];
      float4 c3 = *(const float4*)&sw[(128+op+3)*64+c];
      q0=fmaf(xi[c],a0.x,q0); q0=fmaf(xi[c+1],a0.y,q0); q0=fmaf(xi[c+2],a0.z,q0); q0=fmaf(xi[c+3],a0.w,q0);
      q1=fmaf(xi[c],a1.x,q1); q1=fmaf(xi[c+1],a1.y,q1); q1=fmaf(xi[c+2],a1.z,q1); q1=fmaf(xi[c+3],a1.w,q1);
      q2a=fmaf(xi[c],a2.x,q2a); q2a=fmaf(xi[c+1],a2.y,q2a); q2a=fmaf(xi[c+2],a2.z,q2a); q2a=fmaf(xi[c+3],a2.w,q2a);
      q3=fmaf(xi[c],a3.x,q3); q3=fmaf(xi[c+1],a3.y,q3); q3=fmaf(xi[c+2],a3.z,q3); q3=fmaf(xi[c+3],a3.w,q3);
      r0=fmaf(xi[c],c0.x,r0); r0=fmaf(xi[c+1],c0.y,r0); r0=fmaf(xi[c+2],c0.z,r0); r0=fmaf(xi[c+3],c0.w,r0);
      r1=fmaf(xi[c],c1.x,r1); r1=fmaf(xi[c+1],c1.y,r1); r1=fmaf(xi[c+2],c1.z,r1); r1=fmaf(xi[c+3],c1.w,r1);
      r2a=fmaf(xi[c],c2.x,r2a); r2a=fmaf(xi[c+1],c2.y,r2a); r2a=fmaf(xi[c+2],c2.z,r2a); r2a=fmaf(xi[c+3],c2.w,r2a);
      r3=fmaf(xi[c],c3.x,r3); r3=fmaf(xi[c+1],c3.y,r3); r3=fmaf(xi[c+2],c3.z,r3); r3=fmaf(xi[c+3],c3.w,r3);
    }
    float4 qv; qv.x=q0; qv.y=q1; qv.z=q2a; qv.w=q3;
    float4 rv; rv.x=r0; rv.y=r1; rv.z=r2a; rv.w=r3;
    *(float4*)&q2[(size_t)n*128+op] = qv;
    *(float4*)&r2[(size_t)n*128+op] = rv;
  }
}

// ---------------- edgeconv2 gather + fused mean (never materialize x2) ----------------
__global__ __launch_bounds__(256,4) void ec2_gather_kernel(
    const float* __restrict__ q2, const float* __restrict__ r2,
    const int* __restrict__ idx2, float* __restrict__ fmean){
  __shared__ alignas(16) float4 red[256];
  int t = threadIdx.x;
  int b = blockIdx.x >> 7, blk = blockIdx.x & 127;
  int p = t >> 5, c4 = t & 31;
  int n = b*NP + blk*8 + p;
  float4 r = *(const float4*)&r2[(size_t)n*128 + c4*4];
  float4 acc; acc.x=0; acc.y=0; acc.z=0; acc.w=0;
  #pragma unroll 1
  for (int k=0;k<KNN;++k){
    int j = idx2[n*KNN+k];
    float4 qv = *(const float4*)&q2[((size_t)b*NP + j)*128 + c4*4];
    acc.x += lrelu(r.x+qv.x);
    acc.y += lrelu(r.y+qv.y);
    acc.z += lrelu(r.z+qv.z);
    acc.w += lrelu(r.w+qv.w);
  }
  red[t] = acc;
  __syncthreads();
  if (t < 128){ float4 o = red[t+128]; red[t].x+=o.x; red[t].y+=o.y; red[t].z+=o.z; red[t].w+=o.w; }
  __syncthreads();
  if (t < 64){ float4 o = red[t+64]; red[t].x+=o.x; red[t].y+=o.y; red[t].z+=o.z; red[t].w+=o.w; }
  __syncthreads();
  if (t < 32){
    float4 s = red[t]; float4 o = red[t+32];
    s.x+=o.x; s.y+=o.y; s.z+=o.z; s.w+=o.w;
    float* dst = &fmean[b*192 + 64 + c4*4];
    atomicAdd(dst+0, s.x); atomicAdd(dst+1, s.y);
    atomicAdd(dst+2, s.z); atomicAdd(dst+3, s.w);
  }
}

// ---------------- mean of x1 -> fmean[:,0:64] (sums; /1024 applied in head) ----------------
__global__ __launch_bounds__(256,4) void mean1_kernel(const float* __restrict__ x1,
                                                      float* __restrict__ fmean){
  __shared__ float red[256];
  int t = threadIdx.x;
  int b = blockIdx.x >> 2, qq = blockIdx.x & 3;
  int c = t & 63, pl = t >> 6;
  float s = 0.0f;
  for (int i=0;i<64;++i){
    int p = qq*256 + pl + 4*i;
    s += x1[((size_t)b*NP + p)*64 + c];
  }
  red[t] = s;
  __syncthreads();
  if (t < 128) red[t] += red[t+128];
  __syncthreads();
  if (t < 64) atomicAdd(&fmean[b*192 + c], red[t] + red[t+64]);
}

// ---------------- head, split for parallelism ----------------
__global__ __launch_bounds__(256) void headA_kernel(const float* __restrict__ fmean,
    const float* __restrict__ wl, const float* __restrict__ bl,
    float* __restrict__ o1g){
  __shared__ float v0[192];
  int b = blockIdx.x >> 2, ch = blockIdx.x & 3, t = threadIdx.x;
  if (t < 192) v0[t] = fmean[b*192 + t] * (1.0f/1024.0f);
  __syncthreads();
  int o = ch*256 + t;
  float s = bl[o];
  #pragma unroll 8
  for (int c=0;c<192;++c) s = fmaf(v0[c], wl[c*1024 + o], s);
  o1g[b*1024 + o] = s;
}

__global__ __launch_bounds__(256) void headB_kernel(const float* __restrict__ o1g,
    const float* __restrict__ wm1, const float* __restrict__ bm1,
    float* __restrict__ h1g){
  __shared__ alignas(16) float vo[1024];
  int b = blockIdx.x >> 1, ch = blockIdx.x & 1, t = threadIdx.x;
  ((float4*)vo)[t] = ((const float4*)(o1g + b*1024))[t];
  __syncthreads();
  int o = ch*256 + t;
  float s = bm1[o];
  #pragma unroll 8
  for (int c=0;c<1024;++c) s = fmaf(vo[c], wm1[c*512 + o], s);
  h1g[b*512 + o] = lrelu(s);
}

__global__ __launch_bounds__(256) void headC_kernel(const float* __restrict__ h1g,
    const float* __restrict__ wm2, const float* __restrict__ bm2,
    const float* __restrict__ wm3, const float* __restrict__ bm3,
    float* __restrict__ out){
  __shared__ alignas(16) float vh[512];
  __shared__ float h2[256];
  int b = blockIdx.x, t = threadIdx.x;
  ((float2*)vh)[t] = ((const float2*)(h1g + b*512))[t];
  __syncthreads();
  float s = bm2[t];
  #pragma unroll 8
  for (int c=0;c<512;++c) s = fmaf(vh[c], wm2[c*256 + t], s);
  h2[t] = lrelu(s);
  __syncthreads();
  if (t < 3){
    float s2 = bm3[t];
    #pragma unroll 8
    for (int c=0;c<256;++c) s2 = fmaf(h2[c], wm3[c*3 + t], s2);
    out[b*3 + t] = s2;
  }
}

extern "C" void kernel_launch(void* const* d_in, const int* in_sizes, int n_in,
                              void* d_out, int out_size, void* d_ws, size_t ws_size,
                              hipStream_t stream) {
  const float* x   = (const float*)d_in[0];
  const float* pos = (const float*)d_in[1];
  const float* w1a = (const float*)d_in[3];
  const float* b1a = (const float*)d_in[4];
  const float* w1b = (const float*)d_in[5];
  const float* b1b = (const float*)d_in[6];
  const float* w1c = (const float*)d_in[7];
  const float* b1c = (const float*)d_in[8];
  const float* w2  = (const float*)d_in[9];
  const float* b2  = (const float*)d_in[10];
  const float* wl  = (const float*)d_in[11];
  const float* bl  = (const float*)d_in[12];
  const float* wm1 = (const float*)d_in[13];
  const float* bm1 = (const float*)d_in[14];
  const float* wm2 = (const float*)d_in[15];
  const float* bm2 = (const float*)d_in[16];
  const float* wm3 = (const float*)d_in[17];
  const float* bm3 = (const float*)d_in[18];
  float* out = (float*)d_out;

  float* ws_f  = (float*)d_ws;
  float* xx    = ws_f;                    // 262144 f
  float* x1    = xx + 262144;             // 4194304 f (16 MB)
  float* sq2   = x1 + 4194304;            // 65536 f
  int*   idx1  = (int*)(sq2 + 65536);     // 655360 i
  int*   idx2  = idx1 + 655360;           // 655360 i
  float* q2    = (float*)(idx2 + 655360); // 8388608 f (32 MB)
  float* r2    = q2 + 8388608;            // 8388608 f (32 MB)
  float* wcomb = r2 + 8388608;            // 16384 f
  float* fmean = wcomb + 16384;           // 12288 f
  float* o1g   = fmean + 12288;           // 65536 f
  float* h1g   = o1g + 65536;             // 32768 f
  // bdh/bih overlay q2 region: consumed by knn2_merge BEFORE qr2 writes q2
  float* bdh   = q2;                      // 1310720 f (5 MB)
  int*   bih   = (int*)(q2 + 1310720);    // 1310720 i (5 MB)

  zero_fmean<<<48, 256, 0, stream>>>(fmean);
  prep2_kernel<<<64, 256, 0, stream>>>(w2, wcomb);
  build_xx<<<256, 256, 0, stream>>>(x, pos, xx);
  knn1_kernel<<<256, 256, 0, stream>>>(xx, idx1);
  edgeconv1_kernel<<<512, 256, 0, stream>>>(xx, idx1, w1a, b1a, w1b, b1b, w1c, b1c, x1, sq2);
  knn2_kernel<<<256, 256, 0, stream>>>(x1, sq2, bdh, bih);
  knn2_merge<<<256, 256, 0, stream>>>(bdh, bih, idx2);
  qr2_kernel<<<256, 256, 0, stream>>>(x1, wcomb, b2, q2, r2);
  ec2_gather_kernel<<<8192, 256, 0, stream>>>(q2, r2, idx2, fmean);
  mean1_kernel<<<256, 256, 0, stream>>>(x1, fmean);
  headA_kernel<<<256, 256, 0, stream>>>(fmean, wl, bl, o1g);
  headB_kernel<<<128, 256, 0, stream>>>(o1g, wm1, bm1, h1g);
  headC_kernel<<<64, 256, 0, stream>>>(h1g, wm2, bm2, wm3, bm3, out);
}